// Round 14
// baseline (143.982 us; speedup 1.0000x reference)
//
#include <hip/hip_runtime.h>
#include <hip/hip_bf16.h>
#include <stdint.h>

#define N_LEAVES 65536
#define MEM 128
#define HID 128

typedef float  f32x4 __attribute__((ext_vector_type(4)));
typedef short  s16x8 __attribute__((ext_vector_type(8)));
typedef unsigned short u16;
typedef u16    u16x8 __attribute__((ext_vector_type(8)));

__device__ __forceinline__ u16 f2bf(float x) {
    unsigned u = __builtin_bit_cast(unsigned, x);
    u += 0x7FFFu + ((u >> 16) & 1u);          // RNE (prep only)
    return (u16)(u >> 16);
}
__device__ __forceinline__ float bf2f(u16 b) {
    unsigned u = ((unsigned)b) << 16;
    return __builtin_bit_cast(float, u);
}
// truncate-to-bf16 helpers (hi=trunc, lo captures err; combined rel ~2^-16)
__device__ __forceinline__ float hif(float x) {
    return __builtin_bit_cast(float, __builtin_bit_cast(unsigned, x) & 0xffff0000u);
}
// pack trunc-bf16 of (e0,e1) into one dword: low16=bf(e0), high16=bf(e1)
__device__ __forceinline__ unsigned packbf(float e0, float e1) {
    return __builtin_amdgcn_perm(__builtin_bit_cast(unsigned, e1),
                                 __builtin_bit_cast(unsigned, e0), 0x07060302u);
}
// cheap tanh (leaf): absolute err ~1e-7, fine for O(1)-norm activations
__device__ __forceinline__ float tanh_c(float x) {
    float E = __builtin_amdgcn_exp2f(x * 2.8853900817779268f);  // exp(2x)
    return 1.0f - 2.0f * __builtin_amdgcn_rcpf(E + 1.0f);
}
// tree tanh: full RELATIVE accuracy for small |x| (deep-tree h ~ 1e-5)
__device__ __forceinline__ float tanh_p(float x) {
    float x2 = x * x;
    float poly = x * (1.0f + x2 * (-0.33333334f + x2 * 0.13333334f));
    float E = __builtin_amdgcn_exp2f(x * 2.8853900817779268f);
    float ex = 1.0f - 2.0f * __builtin_amdgcn_rcpf(E + 1.0f);
    return (__builtin_fabsf(x) < 0.25f) ? poly : ex;
}

__device__ __forceinline__ f32x4 mfma_bf(s16x8 a, s16x8 b, f32x4 c) {
    return __builtin_amdgcn_mfma_f32_16x16x32_bf16(a, b, c, 0, 0, 0);
}

// ---------------- single prep kernel: split all 6 weights to k-major ----------------
// layout: [(k/8)*N + n]*8 + (k%8), hi/lo planes (RNE split).
__global__ __launch_bounds__(256) void prep_all(
    const float* __restrict__ W1, const float* __restrict__ W2,
    const float* __restrict__ W3, const float* __restrict__ Wp,
    const float* __restrict__ Wand, const float* __restrict__ Wor,
    u16* __restrict__ w1tH, u16* __restrict__ w1tL,
    u16* __restrict__ w2tH, u16* __restrict__ w2tL,
    u16* __restrict__ w3tH, u16* __restrict__ w3tL,
    u16* __restrict__ wptH, u16* __restrict__ wptL,
    u16* __restrict__ waH,  u16* __restrict__ waL,
    u16* __restrict__ woH,  u16* __restrict__ woL)
{
    int g = blockIdx.x * 256 + threadIdx.x;    // one granule (8 elems)
    const float* W; u16 *Th, *Tl; int K, N, base;
    if (g < 1024)       { W = W1;  Th = w1tH; Tl = w1tL; N = 128; K = 64;  base = 0; }
    else if (g < 7168)  { W = W2;  Th = w2tH; Tl = w2tL; N = 384; K = 128; base = 1024; }
    else if (g < 19456) { W = W3;  Th = w3tH; Tl = w3tL; N = 256; K = 384; base = 7168; }
    else if (g < 23552) { W = Wp;  Th = wptH; Tl = wptL; N = 128; K = 256; base = 19456; }
    else if (g < 25600) { W = Wand; Th = waH; Tl = waL;  N = 128; K = 128; base = 23552; }
    else if (g < 27648) { W = Wor;  Th = woH; Tl = woL;  N = 128; K = 128; base = 25600; }
    else return;
    int t = g - base;
    int kg8 = K >> 3;
    int n = t / kg8, kg = t - n * kg8;
    const float* src = &W[(size_t)n * K + kg * 8];
    size_t dst = ((size_t)kg * N + n) * 8;
    u16x8 hv, lv;
    #pragma unroll
    for (int j = 0; j < 8; ++j) {
        float v = src[j];
        u16 hb = f2bf(v);
        hv[j] = hb;
        lv[j] = f2bf(v - bf2f(hb));
    }
    *(u16x8*)&Th[dst] = hv;
    *(u16x8*)&Tl[dst] = lv;
}

// act LDS addressing: 16B granules, XOR-swizzled within each row's stripe.
__device__ __forceinline__ int act_g(int Wu, int row, int c4) {
    return row * (Wu >> 3) + (c4 ^ (row & 7));   // granule index
}

// ------ GEMM core: acc += W(A) x acts(B); per wave: 32 rows (RJ=2) x FJ*16 feats ------
// WINU: act buffer width (u16). WSTR: weight N-stride. kt0: global k offset /32.
// Act buffer holds LOCAL k; weights indexed at kt0+kt. D: weight ring depth.
// T5: setprio(1) around the MFMA cluster (phase-diverse blocks/CU -> scheduler
// can prefer MFMA-issuing waves).
template<int FJ, int KTN, int WINU, int WSTR, int D>
__device__ __forceinline__ void mlp_core(
    f32x4 (&acc)[FJ][2],
    const u16* inH, const u16* inL,
    const u16* __restrict__ BtH, const u16* __restrict__ BtL,
    int kt0, int rowBase, int featBase, int l)
{
    const int lr = l & 15, lc = l >> 4;
    s16x8 wh[D][FJ], wl[D][FJ];
    s16x8 ah[2][2], al[2][2];

    // weight prologue: kt0 .. kt0+D-1
    #pragma unroll
    for (int d = 0; d < D; ++d)
        #pragma unroll
        for (int fi = 0; fi < FJ; ++fi) {
            int o = (((kt0 + d) * 4 + lc) * WSTR + featBase + fi * 16 + lr) * 8;
            wh[d][fi] = *(const s16x8*)&BtH[o];
            wl[d][fi] = *(const s16x8*)&BtL[o];
        }
    // act prologue: kt = 0
    #pragma unroll
    for (int rj = 0; rj < 2; ++rj) {
        int off = act_g(WINU, rowBase + rj * 16 + lr, lc) * 8;
        ah[0][rj] = *(const s16x8*)&inH[off];
        al[0][rj] = *(const s16x8*)&inL[off];
    }

    #pragma unroll
    for (int kt = 0; kt < KTN; ++kt) {
        const int ws_ = kt % D;
        const int as_ = kt & 1;
        if (kt + 1 < KTN) {
            #pragma unroll
            for (int rj = 0; rj < 2; ++rj) {
                int off = act_g(WINU, rowBase + rj * 16 + lr, (kt + 1) * 4 + lc) * 8;
                ah[as_ ^ 1][rj] = *(const s16x8*)&inH[off];
                al[as_ ^ 1][rj] = *(const s16x8*)&inL[off];
            }
        }
        __builtin_amdgcn_s_setprio(1);
        #pragma unroll
        for (int fi = 0; fi < FJ; ++fi)
            #pragma unroll
            for (int rj = 0; rj < 2; ++rj) {
                f32x4 a = acc[fi][rj];
                a = mfma_bf(wh[ws_][fi], ah[as_][rj], a);
                a = mfma_bf(wh[ws_][fi], al[as_][rj], a);
                a = mfma_bf(wl[ws_][fi], ah[as_][rj], a);
                acc[fi][rj] = a;
            }
        __builtin_amdgcn_s_setprio(0);
        if (kt + D < KTN) {
            #pragma unroll
            for (int fi = 0; fi < FJ; ++fi) {
                int o = (((kt0 + kt + D) * 4 + lc) * WSTR + featBase + fi * 16 + lr) * 8;
                wh[ws_][fi] = *(const s16x8*)&BtH[o];
                wl[ws_][fi] = *(const s16x8*)&BtL[o];
            }
        }
    }
}

// epilogue: tanh + trunc-split + perm-pack, to LDS act planes of width WOUTU
template<int FJ, int WOUTU>
__device__ __forceinline__ void write_act(
    f32x4 (&acc)[FJ][2], u16* outH, u16* outL, int rowBase, int featBase, int l)
{
    const int lr = l & 15, lc = l >> 4;
    #pragma unroll
    for (int fi = 0; fi < FJ; ++fi)
        #pragma unroll
        for (int rj = 0; rj < 2; ++rj) {
            int m  = rowBase + rj * 16 + lr;
            int n0 = featBase + fi * 16 + lc * 4;
            f32x4 v = acc[fi][rj];
            float t0 = tanh_c(v[0]), t1 = tanh_c(v[1]);
            float t2 = tanh_c(v[2]), t3 = tanh_c(v[3]);
            uint2 hp, lp;
            hp.x = packbf(t0, t1);
            hp.y = packbf(t2, t3);
            lp.x = packbf(t0 - hif(t0), t1 - hif(t1));
            lp.y = packbf(t2 - hif(t2), t3 - hif(t3));
            int go = act_g(WOUTU, m, n0 >> 3) * 8 + (n0 & 7);
            *(uint2*)&outH[go] = hp;
            *(uint2*)&outL[go] = lp;
        }
}

// ---------------- one tree level (acts=A so lane's 4 D-rows = one parent) -------
template<int CJ, int FJ, bool TOGLOBAL>
__device__ __forceinline__ void tree_level(
    const u16* inH, const u16* inL,                   // LDS act planes, width 128
    const u16* __restrict__ wAH, const u16* __restrict__ wAL,
    const u16* __restrict__ wOH, const u16* __restrict__ wOL,  // k-major global
    const int* __restrict__ opsL,
    u16* outH, u16* outL,
    int outRowBase, int nValid, int cfBase, int ffBase, int l)
{
    const int lr = l & 15, lc = l >> 4;
    f32x4 accA[CJ][FJ] = {};
    f32x4 accO[CJ][FJ] = {};

    #pragma unroll
    for (int kt = 0; kt < 4; ++kt) {
        s16x8 ah[CJ], al[CJ];
        #pragma unroll
        for (int c = 0; c < CJ; ++c) {
            int off = act_g(128, (cfBase + c) * 16 + lr, kt * 4 + lc) * 8;
            ah[c] = *(const s16x8*)&inH[off];
            al[c] = *(const s16x8*)&inL[off];
        }
        #pragma unroll
        for (int f = 0; f < FJ; ++f) {
            int wo = ((kt * 4 + lc) * 128 + ffBase + f * 16 + lr) * 8;
            s16x8 bah = *(const s16x8*)&wAH[wo];
            s16x8 bal = *(const s16x8*)&wAL[wo];
            s16x8 boh = *(const s16x8*)&wOH[wo];
            s16x8 bol = *(const s16x8*)&wOL[wo];
            __builtin_amdgcn_s_setprio(1);
            #pragma unroll
            for (int c = 0; c < CJ; ++c) {
                f32x4 a = accA[c][f];
                a = mfma_bf(ah[c], bah, a);
                a = mfma_bf(ah[c], bal, a);
                a = mfma_bf(al[c], bah, a);
                accA[c][f] = a;
                f32x4 o = accO[c][f];
                o = mfma_bf(ah[c], boh, o);
                o = mfma_bf(ah[c], bol, o);
                o = mfma_bf(al[c], boh, o);
                accO[c][f] = o;
            }
            __builtin_amdgcn_s_setprio(0);
        }
    }

    #pragma unroll
    for (int c = 0; c < CJ; ++c) {
        int p = (cfBase + c) * 4 + lc;
        if (p < nValid) {
            int op = opsL[p];
            #pragma unroll
            for (int f = 0; f < FJ; ++f) {
                f32x4 v = op ? accO[c][f] : accA[c][f];
                float t = 0.25f * (tanh_p(v[0]) + tanh_p(v[1]) + tanh_p(v[2]) + tanh_p(v[3]));
                unsigned bits = __builtin_bit_cast(unsigned, t);
                u16 hb = (u16)(bits >> 16);
                float lof = t - __builtin_bit_cast(float, bits & 0xffff0000u);
                u16 lb = (u16)(__builtin_bit_cast(unsigned, lof) >> 16);
                int feat = ffBase + f * 16 + lr;
                if constexpr (TOGLOBAL) {
                    int ga = (outRowBase + p) * 128 + feat;
                    outH[ga] = hb;
                    outL[ga] = lb;
                } else {
                    int go = act_g(128, outRowBase + p, feat >> 3) * 8 + (feat & 7);
                    outH[go] = hb;
                    outL[go] = lb;
                }
            }
        }
    }
}

// --- fused leaf MLP + tree L7: 64 rows/block, 8 waves as 2 row-grp x 4 feat-grp ---
// 64KB LDS (2 blocks/CU); L2->L3 streamed through a 128-feature chunk buffer.
__global__ __launch_bounds__(512, 4) void leaf_fused(
    const float* __restrict__ x,                 // [65536][64] fp32
    const u16* __restrict__ W1tH, const u16* __restrict__ W1tL,
    const u16* __restrict__ W2tH, const u16* __restrict__ W2tL,
    const u16* __restrict__ W3tH, const u16* __restrict__ W3tL,
    const u16* __restrict__ WptH, const u16* __restrict__ WptL,
    const u16* __restrict__ waH,  const u16* __restrict__ waL,
    const u16* __restrict__ woH,  const u16* __restrict__ woL,
    const int* __restrict__ ops,
    u16* __restrict__ l7H, u16* __restrict__ l7L) // [16384][128]
{
    __shared__ u16 pool[32768];   // 64 KB

    // regions (u16 offsets):
    u16* h1H = pool;               u16* h1L = pool + 8192;    // [0,16384)   w=128
    u16* xH  = pool + 16384;       u16* xL  = pool + 20480;   // [16384,24576) w=64
    u16* h2H = pool + 16384;       u16* h2L = pool + 24576;   // [16384,32768) w=128 (over x)
    u16* h3H = pool;               u16* h3L = pool + 16384;   // [0,32768)   w=256 (over h1+h2)
    u16* h4H = pool;               u16* h4L = pool + 8192;    // [0,16384)   w=128 (over h3)

    const int tid = threadIdx.x;
    const int w = tid >> 6, l = tid & 63;
    const int rg = w >> 2;          // row group: rows rg*32 .. rg*32+31
    const int fg = w & 3;           // feature group
    const int rowB = rg * 32;
    const int blk = blockIdx.x;
    const int rowBase = blk * 64;

    // stage x: 1 granule/thread, swizzled, trunc-split
    {
        int row = tid >> 3;
        int c0  = (tid & 7) * 8;
        const float* src = &x[(size_t)(rowBase + row) * 64 + c0];
        float4 v0 = *(const float4*)src;
        float4 v1 = *(const float4*)(src + 4);
        float xs[8] = {v0.x, v0.y, v0.z, v0.w, v1.x, v1.y, v1.z, v1.w};
        int go = act_g(64, row, c0 >> 3) * 8;
        uint4 hp, lp;
        hp.x = packbf(xs[0], xs[1]); hp.y = packbf(xs[2], xs[3]);
        hp.z = packbf(xs[4], xs[5]); hp.w = packbf(xs[6], xs[7]);
        lp.x = packbf(xs[0] - hif(xs[0]), xs[1] - hif(xs[1]));
        lp.y = packbf(xs[2] - hif(xs[2]), xs[3] - hif(xs[3]));
        lp.z = packbf(xs[4] - hif(xs[4]), xs[5] - hif(xs[5]));
        lp.w = packbf(xs[6] - hif(xs[6]), xs[7] - hif(xs[7]));
        *(uint4*)&xH[go] = hp;
        *(uint4*)&xL[go] = lp;
    }
    __syncthreads();

    // L1: 64 -> 128
    {
        f32x4 acc1[2][2] = {};
        mlp_core<2, 2, 64, 128, 2>(acc1, xH, xL, W1tH, W1tL, 0, rowB, fg * 32, l);
        write_act<2, 128>(acc1, h1H, h1L, rowB, fg * 32, l);
    }
    __syncthreads();

    // L2 -> L3 streamed in three 128-feature passes; L3 accs persist in regs
    f32x4 acc3[4][2] = {};
    #pragma unroll
    for (int p = 0; p < 3; ++p) {
        if (p) __syncthreads();            // prior pass's L3 readers done
        {
            f32x4 acc2[2][2] = {};
            mlp_core<2, 4, 128, 384, 2>(acc2, h1H, h1L, W2tH, W2tL, 0,
                                        rowB, p * 128 + fg * 32, l);
            write_act<2, 128>(acc2, h2H, h2L, rowB, fg * 32, l);
        }
        __syncthreads();                   // h2 chunk ready
        mlp_core<4, 4, 128, 256, 1>(acc3, h2H, h2L, W3tH, W3tL, p * 4,
                                    rowB, fg * 64, l);
    }
    __syncthreads();                       // all h2/h1 readers done
    write_act<4, 256>(acc3, h3H, h3L, rowB, fg * 64, l);   // h3 over h1+h2
    __syncthreads();

    // L4: 256 -> 128
    {
        f32x4 acc4[2][2] = {};
        mlp_core<2, 8, 256, 128, 2>(acc4, h3H, h3L, WptH, WptL, 0, rowB, fg * 32, l);
        __syncthreads();                   // h3 readers done
        write_act<2, 128>(acc4, h4H, h4L, rowB, fg * 32, l);  // h4 over h3 start
    }
    __syncthreads();

    // tree level 7: 64 rows -> 16 parents, straight to global l7
    tree_level<1, 4, true>(h4H, h4L, waH, waL, woH, woL,
                           ops + 5461 + blk * 16, l7H, l7L,
                           blk * 16, 16, (w >> 1), (w & 1) * 64, l);
}

// ---------------- fused 3-level tree kernel: 128 child rows -> 2 parents --------
__global__ __launch_bounds__(512, 4) void tree3(
    const u16* __restrict__ inH, const u16* __restrict__ inL,   // [blocks*128][128]
    const u16* __restrict__ wAH, const u16* __restrict__ wAL,
    const u16* __restrict__ wOH, const u16* __restrict__ wOL,
    const int* __restrict__ ops0, const int* __restrict__ ops1,
    const int* __restrict__ ops2,
    u16* __restrict__ outH, u16* __restrict__ outL)             // [blocks*2][128]
{
    __shared__ u16 L0H[16384], L0L[16384];   // 128 rows (reused by level c out)
    __shared__ u16 L1H[4096],  L1L[4096];    // 32 rows

    const int tid = threadIdx.x;
    const int w = tid >> 6, l = tid & 63;
    const int blk = blockIdx.x;

    #pragma unroll
    for (int it = 0; it < 4; ++it) {
        int g = tid + it * 512;              // granule 0..2047
        int row = g >> 4, c4 = g & 15;
        size_t src = (size_t)(blk * 128 + row) * 128 + c4 * 8;
        int dst = act_g(128, row, c4) * 8;
        *(u16x8*)&L0H[dst] = *(const u16x8*)&inH[src];
        *(u16x8*)&L0L[dst] = *(const u16x8*)&inL[src];
    }
    __syncthreads();

    // level a: 128 rows -> 32 parents
    tree_level<2, 4, false>(L0H, L0L, wAH, wAL, wOH, wOL, ops0 + blk * 32,
                            L1H, L1L, 0, 32, (w & 3) * 2, (w >> 2) * 64, l);
    __syncthreads();
    // level b: 32 rows -> 8 parents (into L0 region, rows 0..7)
    tree_level<1, 2, false>(L1H, L1L, wAH, wAL, wOH, wOL, ops1 + blk * 8,
                            L0H, L0L, 0, 8, (w >> 2), (w & 3) * 32, l);
    __syncthreads();
    // level c: 8 rows -> 2 parents, to global
    tree_level<1, 1, true>(L0H, L0L, wAH, wAL, wOH, wOL, ops2 + blk * 2,
                           outH, outL, blk * 2, 2, 0, w * 16, l);
}

// ---------------- tail: level 0 + readout (fp32, float4 dots) ----------------
__global__ __launch_bounds__(128) void tail_final(
    const u16* __restrict__ l1H, const u16* __restrict__ l1L,   // [4][128]
    const int* __restrict__ ops,
    const float* __restrict__ Wand, const float* __restrict__ Wor,
    const float* __restrict__ Rw1, const float* __restrict__ Rb1,
    const float* __restrict__ Rw2, const float* __restrict__ Rb2,
    const float* __restrict__ Rw3, const float* __restrict__ Rb3,
    const float* __restrict__ Rwp, const float* __restrict__ Rbp,
    float* __restrict__ out)
{
    __shared__ float h[512];
    __shared__ float F[512];
    const int o = threadIdx.x;

    for (int i = o; i < 512; i += 128) h[i] = bf2f(l1H[i]) + bf2f(l1L[i]);
    __syncthreads();

    // level 0: root
    {
        const float* Wsel = (ops[0] == 0) ? Wand : Wor;
        const float4* wr = (const float4*)&Wsel[o * 128];
        const float4* h0 = (const float4*)&h[0];
        const float4* h1 = (const float4*)&h[128];
        const float4* h2 = (const float4*)&h[256];
        const float4* h3 = (const float4*)&h[384];
        float s0 = 0, s1 = 0, s2 = 0, s3 = 0;
        for (int m = 0; m < 32; ++m) {
            float4 wv = wr[m];
            float4 a0 = h0[m], a1 = h1[m], a2 = h2[m], a3 = h3[m];
            s0 += wv.x*a0.x + wv.y*a0.y + wv.z*a0.z + wv.w*a0.w;
            s1 += wv.x*a1.x + wv.y*a1.y + wv.z*a1.z + wv.w*a1.w;
            s2 += wv.x*a2.x + wv.y*a2.y + wv.z*a2.z + wv.w*a2.w;
            s3 += wv.x*a3.x + wv.y*a3.y + wv.z*a3.z + wv.w*a3.w;
        }
        F[o] = 0.25f * (tanh_p(s0) + tanh_p(s1) + tanh_p(s2) + tanh_p(s3));
    }
    __syncthreads();
    {
        const float4* wr = (const float4*)&Rw1[o * 128];
        const float4* xr = (const float4*)&F[0];
        float s = 0;
        for (int m = 0; m < 32; ++m) {
            float4 wv = wr[m], xv = xr[m];
            s += wv.x*xv.x + wv.y*xv.y + wv.z*xv.z + wv.w*xv.w;
        }
        __syncthreads();
        F[128 + o] = fmaxf(s + Rb1[o], 0.f);
    }
    __syncthreads();
    {
        const float4* wr = (const float4*)&Rw2[o * 128];
        const float4* xr = (const float4*)&F[128];
        float s = 0;
        for (int m = 0; m < 32; ++m) {
            float4 wv = wr[m], xv = xr[m];
            s += wv.x*xv.x + wv.y*xv.y + wv.z*xv.z + wv.w*xv.w;
        }
        __syncthreads();
        F[256 + o] = fmaxf(s + Rb2[o], 0.f);
    }
    __syncthreads();
    {
        const float4* wr = (const float4*)&Rw3[o * 128];
        const float4* xr = (const float4*)&F[256];
        float s = 0;
        for (int m = 0; m < 32; ++m) {
            float4 wv = wr[m], xv = xr[m];
            s += wv.x*xv.x + wv.y*xv.y + wv.z*xv.z + wv.w*xv.w;
        }
        __syncthreads();
        F[384 + o] = fmaxf(s + Rb3[o], 0.f) * Rwp[o];
    }
    __syncthreads();
    if (o == 0) {
        float t = 0.f;
        for (int i = 0; i < 128; ++i) t += F[384 + i];
        out[0] = t + Rbp[0];
    }
}

// ---------------- host launch ----------------
extern "C" void kernel_launch(void* const* d_in, const int* in_sizes, int n_in,
                              void* d_out, int out_size, void* d_ws, size_t ws_size,
                              hipStream_t stream)
{
    const float* inputs = (const float*)d_in[0];
    const int*   ops    = (const int*)d_in[1];
    const float* W1     = (const float*)d_in[2];
    const float* W2     = (const float*)d_in[3];
    const float* W3     = (const float*)d_in[4];
    const float* Wp     = (const float*)d_in[5];
    const float* Wand   = (const float*)d_in[6];
    const float* Wor    = (const float*)d_in[7];
    const float* Rw1    = (const float*)d_in[8];
    const float* Rb1    = (const float*)d_in[9];
    const float* Rw2    = (const float*)d_in[10];
    const float* Rb2    = (const float*)d_in[11];
    const float* Rw3    = (const float*)d_in[12];
    const float* Rb3    = (const float*)d_in[13];
    const float* Rwp    = (const float*)d_in[14];
    const float* Rbp    = (const float*)d_in[15];
    float* out = (float*)d_out;
    u16* ws = (u16*)d_ws;

    // ---- workspace layout (u16 elements) ----
    size_t off = 0;
    u16* w1tH = ws + off; off += 8192;   u16* w1tL = ws + off; off += 8192;
    u16* w2tH = ws + off; off += 49152;  u16* w2tL = ws + off; off += 49152;
    u16* w3tH = ws + off; off += 98304;  u16* w3tL = ws + off; off += 98304;
    u16* wptH = ws + off; off += 32768;  u16* wptL = ws + off; off += 32768;
    u16* waH  = ws + off; off += 16384;  u16* waL  = ws + off; off += 16384;
    u16* woH  = ws + off; off += 16384;  u16* woL  = ws + off; off += 16384;
    u16* l7H  = ws + off; off += (size_t)16384 * 128;
    u16* l7L  = ws + off; off += (size_t)16384 * 128;
    u16* l4H  = ws + off; off += 256 * 128;
    u16* l4L  = ws + off; off += 256 * 128;
    u16* l1H  = ws + off; off += 512;
    u16* l1L  = ws + off; off += 512;

    // ---- weight prep ----
    prep_all<<<108, 256, 0, stream>>>(W1, W2, W3, Wp, Wand, Wor,
        w1tH, w1tL, w2tH, w2tL, w3tH, w3tL, wptH, wptL, waH, waL, woH, woL);

    // ---- fused leaf MLP + tree level 7 (1024 blocks, 64KB LDS) ----
    leaf_fused<<<N_LEAVES / 64, 512, 0, stream>>>(
        inputs, w1tH, w1tL, w2tH, w2tL, w3tH, w3tL, wptH, wptL,
        waH, waL, woH, woL, ops, l7H, l7L);

    // ---- tree levels 6,5,4 (128 blocks) ----
    tree3<<<128, 512, 0, stream>>>(l7H, l7L, waH, waL, woH, woL,
        ops + 1365, ops + 341, ops + 85, l4H, l4L);

    // ---- tree levels 3,2,1 (2 blocks) ----
    tree3<<<2, 512, 0, stream>>>(l4H, l4L, waH, waL, woH, woL,
        ops + 21, ops + 5, ops + 1, l1H, l1L);

    // ---- level 0 + readout ----
    tail_final<<<1, 128, 0, stream>>>(l1H, l1L, ops, Wand, Wor,
        Rw1, Rb1, Rw2, Rb2, Rw3, Rb3, Rwp, Rbp, out);
}

// Round 15
// 142.095 us; speedup vs baseline: 1.0133x; 1.0133x over previous
//
#include <hip/hip_runtime.h>
#include <hip/hip_bf16.h>
#include <stdint.h>

#define N_LEAVES 65536
#define MEM 128
#define HID 128

typedef float  f32x4 __attribute__((ext_vector_type(4)));
typedef short  s16x8 __attribute__((ext_vector_type(8)));
typedef unsigned short u16;
typedef u16    u16x8 __attribute__((ext_vector_type(8)));

__device__ __forceinline__ u16 f2bf(float x) {
    unsigned u = __builtin_bit_cast(unsigned, x);
    u += 0x7FFFu + ((u >> 16) & 1u);          // RNE (prep only)
    return (u16)(u >> 16);
}
__device__ __forceinline__ float bf2f(u16 b) {
    unsigned u = ((unsigned)b) << 16;
    return __builtin_bit_cast(float, u);
}
// truncate-to-bf16 helpers (hi=trunc, lo captures err; combined rel ~2^-16)
__device__ __forceinline__ float hif(float x) {
    return __builtin_bit_cast(float, __builtin_bit_cast(unsigned, x) & 0xffff0000u);
}
// pack trunc-bf16 of (e0,e1) into one dword: low16=bf(e0), high16=bf(e1)
__device__ __forceinline__ unsigned packbf(float e0, float e1) {
    return __builtin_amdgcn_perm(__builtin_bit_cast(unsigned, e1),
                                 __builtin_bit_cast(unsigned, e0), 0x07060302u);
}
// cheap tanh (leaf): absolute err ~1e-7, fine for O(1)-norm activations
__device__ __forceinline__ float tanh_c(float x) {
    float E = __builtin_amdgcn_exp2f(x * 2.8853900817779268f);  // exp(2x)
    return 1.0f - 2.0f * __builtin_amdgcn_rcpf(E + 1.0f);
}
// tree tanh: full RELATIVE accuracy for small |x| (deep-tree h ~ 1e-5)
__device__ __forceinline__ float tanh_p(float x) {
    float x2 = x * x;
    float poly = x * (1.0f + x2 * (-0.33333334f + x2 * 0.13333334f));
    float E = __builtin_amdgcn_exp2f(x * 2.8853900817779268f);
    float ex = 1.0f - 2.0f * __builtin_amdgcn_rcpf(E + 1.0f);
    return (__builtin_fabsf(x) < 0.25f) ? poly : ex;
}

__device__ __forceinline__ f32x4 mfma_bf(s16x8 a, s16x8 b, f32x4 c) {
    return __builtin_amdgcn_mfma_f32_16x16x32_bf16(a, b, c, 0, 0, 0);
}

// ---------------- single prep kernel: split all 6 weights to k-major ----------------
// layout: [(k/8)*N + n]*8 + (k%8), hi/lo planes (RNE split).
__global__ __launch_bounds__(256) void prep_all(
    const float* __restrict__ W1, const float* __restrict__ W2,
    const float* __restrict__ W3, const float* __restrict__ Wp,
    const float* __restrict__ Wand, const float* __restrict__ Wor,
    u16* __restrict__ w1tH, u16* __restrict__ w1tL,
    u16* __restrict__ w2tH, u16* __restrict__ w2tL,
    u16* __restrict__ w3tH, u16* __restrict__ w3tL,
    u16* __restrict__ wptH, u16* __restrict__ wptL,
    u16* __restrict__ waH,  u16* __restrict__ waL,
    u16* __restrict__ woH,  u16* __restrict__ woL)
{
    int g = blockIdx.x * 256 + threadIdx.x;    // one granule (8 elems)
    const float* W; u16 *Th, *Tl; int K, N, base;
    if (g < 1024)       { W = W1;  Th = w1tH; Tl = w1tL; N = 128; K = 64;  base = 0; }
    else if (g < 7168)  { W = W2;  Th = w2tH; Tl = w2tL; N = 384; K = 128; base = 1024; }
    else if (g < 19456) { W = W3;  Th = w3tH; Tl = w3tL; N = 256; K = 384; base = 7168; }
    else if (g < 23552) { W = Wp;  Th = wptH; Tl = wptL; N = 128; K = 256; base = 19456; }
    else if (g < 25600) { W = Wand; Th = waH; Tl = waL;  N = 128; K = 128; base = 23552; }
    else if (g < 27648) { W = Wor;  Th = woH; Tl = woL;  N = 128; K = 128; base = 25600; }
    else return;
    int t = g - base;
    int kg8 = K >> 3;
    int n = t / kg8, kg = t - n * kg8;
    const float* src = &W[(size_t)n * K + kg * 8];
    size_t dst = ((size_t)kg * N + n) * 8;
    u16x8 hv, lv;
    #pragma unroll
    for (int j = 0; j < 8; ++j) {
        float v = src[j];
        u16 hb = f2bf(v);
        hv[j] = hb;
        lv[j] = f2bf(v - bf2f(hb));
    }
    *(u16x8*)&Th[dst] = hv;
    *(u16x8*)&Tl[dst] = lv;
}

// act LDS addressing: 16B granules, XOR-swizzled within each row's stripe.
__device__ __forceinline__ int act_g(int Wu, int row, int c4) {
    return row * (Wu >> 3) + (c4 ^ (row & 7));   // granule index
}

// ------ GEMM core: acc += W(A) x acts(B); per wave: 32 rows (RJ=2) x FJ*16 feats ------
// WINU: act buffer width (u16). WSTR: weight N-stride. kt0: global k offset /32.
// Act buffer holds LOCAL k; weights indexed at kt0+kt. D: weight ring depth.
template<int FJ, int KTN, int WINU, int WSTR, int D>
__device__ __forceinline__ void mlp_core(
    f32x4 (&acc)[FJ][2],
    const u16* inH, const u16* inL,
    const u16* __restrict__ BtH, const u16* __restrict__ BtL,
    int kt0, int rowBase, int featBase, int l)
{
    const int lr = l & 15, lc = l >> 4;
    s16x8 wh[D][FJ], wl[D][FJ];
    s16x8 ah[2][2], al[2][2];

    // weight prologue: kt0 .. kt0+D-1
    #pragma unroll
    for (int d = 0; d < D; ++d)
        #pragma unroll
        for (int fi = 0; fi < FJ; ++fi) {
            int o = (((kt0 + d) * 4 + lc) * WSTR + featBase + fi * 16 + lr) * 8;
            wh[d][fi] = *(const s16x8*)&BtH[o];
            wl[d][fi] = *(const s16x8*)&BtL[o];
        }
    // act prologue: kt = 0
    #pragma unroll
    for (int rj = 0; rj < 2; ++rj) {
        int off = act_g(WINU, rowBase + rj * 16 + lr, lc) * 8;
        ah[0][rj] = *(const s16x8*)&inH[off];
        al[0][rj] = *(const s16x8*)&inL[off];
    }

    #pragma unroll
    for (int kt = 0; kt < KTN; ++kt) {
        const int ws_ = kt % D;
        const int as_ = kt & 1;
        if (kt + 1 < KTN) {
            #pragma unroll
            for (int rj = 0; rj < 2; ++rj) {
                int off = act_g(WINU, rowBase + rj * 16 + lr, (kt + 1) * 4 + lc) * 8;
                ah[as_ ^ 1][rj] = *(const s16x8*)&inH[off];
                al[as_ ^ 1][rj] = *(const s16x8*)&inL[off];
            }
        }
        #pragma unroll
        for (int fi = 0; fi < FJ; ++fi)
            #pragma unroll
            for (int rj = 0; rj < 2; ++rj) {
                f32x4 a = acc[fi][rj];
                a = mfma_bf(wh[ws_][fi], ah[as_][rj], a);
                a = mfma_bf(wh[ws_][fi], al[as_][rj], a);
                a = mfma_bf(wl[ws_][fi], ah[as_][rj], a);
                acc[fi][rj] = a;
            }
        if (kt + D < KTN) {
            #pragma unroll
            for (int fi = 0; fi < FJ; ++fi) {
                int o = (((kt0 + kt + D) * 4 + lc) * WSTR + featBase + fi * 16 + lr) * 8;
                wh[ws_][fi] = *(const s16x8*)&BtH[o];
                wl[ws_][fi] = *(const s16x8*)&BtL[o];
            }
        }
    }
}

// epilogue: tanh + trunc-split + perm-pack, to LDS act planes of width WOUTU
template<int FJ, int WOUTU>
__device__ __forceinline__ void write_act(
    f32x4 (&acc)[FJ][2], u16* outH, u16* outL, int rowBase, int featBase, int l)
{
    const int lr = l & 15, lc = l >> 4;
    #pragma unroll
    for (int fi = 0; fi < FJ; ++fi)
        #pragma unroll
        for (int rj = 0; rj < 2; ++rj) {
            int m  = rowBase + rj * 16 + lr;
            int n0 = featBase + fi * 16 + lc * 4;
            f32x4 v = acc[fi][rj];
            float t0 = tanh_c(v[0]), t1 = tanh_c(v[1]);
            float t2 = tanh_c(v[2]), t3 = tanh_c(v[3]);
            uint2 hp, lp;
            hp.x = packbf(t0, t1);
            hp.y = packbf(t2, t3);
            lp.x = packbf(t0 - hif(t0), t1 - hif(t1));
            lp.y = packbf(t2 - hif(t2), t3 - hif(t3));
            int go = act_g(WOUTU, m, n0 >> 3) * 8 + (n0 & 7);
            *(uint2*)&outH[go] = hp;
            *(uint2*)&outL[go] = lp;
        }
}

// ---------------- one tree level (acts=A so lane's 4 D-rows = one parent) -------
template<int CJ, int FJ, bool TOGLOBAL>
__device__ __forceinline__ void tree_level(
    const u16* inH, const u16* inL,                   // LDS act planes, width 128
    const u16* __restrict__ wAH, const u16* __restrict__ wAL,
    const u16* __restrict__ wOH, const u16* __restrict__ wOL,  // k-major global
    const int* __restrict__ opsL,
    u16* outH, u16* outL,
    int outRowBase, int nValid, int cfBase, int ffBase, int l)
{
    const int lr = l & 15, lc = l >> 4;
    f32x4 accA[CJ][FJ] = {};
    f32x4 accO[CJ][FJ] = {};

    #pragma unroll
    for (int kt = 0; kt < 4; ++kt) {
        s16x8 ah[CJ], al[CJ];
        #pragma unroll
        for (int c = 0; c < CJ; ++c) {
            int off = act_g(128, (cfBase + c) * 16 + lr, kt * 4 + lc) * 8;
            ah[c] = *(const s16x8*)&inH[off];
            al[c] = *(const s16x8*)&inL[off];
        }
        #pragma unroll
        for (int f = 0; f < FJ; ++f) {
            int wo = ((kt * 4 + lc) * 128 + ffBase + f * 16 + lr) * 8;
            s16x8 bah = *(const s16x8*)&wAH[wo];
            s16x8 bal = *(const s16x8*)&wAL[wo];
            s16x8 boh = *(const s16x8*)&wOH[wo];
            s16x8 bol = *(const s16x8*)&wOL[wo];
            #pragma unroll
            for (int c = 0; c < CJ; ++c) {
                f32x4 a = accA[c][f];
                a = mfma_bf(ah[c], bah, a);
                a = mfma_bf(ah[c], bal, a);
                a = mfma_bf(al[c], bah, a);
                accA[c][f] = a;
                f32x4 o = accO[c][f];
                o = mfma_bf(ah[c], boh, o);
                o = mfma_bf(ah[c], bol, o);
                o = mfma_bf(al[c], boh, o);
                accO[c][f] = o;
            }
        }
    }

    #pragma unroll
    for (int c = 0; c < CJ; ++c) {
        int p = (cfBase + c) * 4 + lc;
        if (p < nValid) {
            int op = opsL[p];
            #pragma unroll
            for (int f = 0; f < FJ; ++f) {
                f32x4 v = op ? accO[c][f] : accA[c][f];
                float t = 0.25f * (tanh_p(v[0]) + tanh_p(v[1]) + tanh_p(v[2]) + tanh_p(v[3]));
                unsigned bits = __builtin_bit_cast(unsigned, t);
                u16 hb = (u16)(bits >> 16);
                float lof = t - __builtin_bit_cast(float, bits & 0xffff0000u);
                u16 lb = (u16)(__builtin_bit_cast(unsigned, lof) >> 16);
                int feat = ffBase + f * 16 + lr;
                if constexpr (TOGLOBAL) {
                    int ga = (outRowBase + p) * 128 + feat;
                    outH[ga] = hb;
                    outL[ga] = lb;
                } else {
                    int go = act_g(128, outRowBase + p, feat >> 3) * 8 + (feat & 7);
                    outH[go] = hb;
                    outL[go] = lb;
                }
            }
        }
    }
}

// --- fused leaf MLP + tree L7: 64 rows/block, 8 waves as 2 row-grp x 4 feat-grp ---
// 64KB LDS (2 blocks/CU); L2->L3 streamed through a 128-feature chunk buffer.
// L3 split into two FJ=2/D=2 calls so its weight ring has 1-kt prefetch distance.
__global__ __launch_bounds__(512, 4) void leaf_fused(
    const float* __restrict__ x,                 // [65536][64] fp32
    const u16* __restrict__ W1tH, const u16* __restrict__ W1tL,
    const u16* __restrict__ W2tH, const u16* __restrict__ W2tL,
    const u16* __restrict__ W3tH, const u16* __restrict__ W3tL,
    const u16* __restrict__ WptH, const u16* __restrict__ WptL,
    const u16* __restrict__ waH,  const u16* __restrict__ waL,
    const u16* __restrict__ woH,  const u16* __restrict__ woL,
    const int* __restrict__ ops,
    u16* __restrict__ l7H, u16* __restrict__ l7L) // [16384][128]
{
    __shared__ u16 pool[32768];   // 64 KB

    // regions (u16 offsets):
    u16* h1H = pool;               u16* h1L = pool + 8192;    // [0,16384)   w=128
    u16* xH  = pool + 16384;       u16* xL  = pool + 20480;   // [16384,24576) w=64
    u16* h2H = pool + 16384;       u16* h2L = pool + 24576;   // [16384,32768) w=128 (over x)
    u16* h3H = pool;               u16* h3L = pool + 16384;   // [0,32768)   w=256 (over h1+h2)
    u16* h4H = pool;               u16* h4L = pool + 8192;    // [0,16384)   w=128 (over h3)

    const int tid = threadIdx.x;
    const int w = tid >> 6, l = tid & 63;
    const int rg = w >> 2;          // row group: rows rg*32 .. rg*32+31
    const int fg = w & 3;           // feature group
    const int rowB = rg * 32;
    const int blk = blockIdx.x;
    const int rowBase = blk * 64;

    // stage x: 1 granule/thread, swizzled, trunc-split
    {
        int row = tid >> 3;
        int c0  = (tid & 7) * 8;
        const float* src = &x[(size_t)(rowBase + row) * 64 + c0];
        float4 v0 = *(const float4*)src;
        float4 v1 = *(const float4*)(src + 4);
        float xs[8] = {v0.x, v0.y, v0.z, v0.w, v1.x, v1.y, v1.z, v1.w};
        int go = act_g(64, row, c0 >> 3) * 8;
        uint4 hp, lp;
        hp.x = packbf(xs[0], xs[1]); hp.y = packbf(xs[2], xs[3]);
        hp.z = packbf(xs[4], xs[5]); hp.w = packbf(xs[6], xs[7]);
        lp.x = packbf(xs[0] - hif(xs[0]), xs[1] - hif(xs[1]));
        lp.y = packbf(xs[2] - hif(xs[2]), xs[3] - hif(xs[3]));
        lp.z = packbf(xs[4] - hif(xs[4]), xs[5] - hif(xs[5]));
        lp.w = packbf(xs[6] - hif(xs[6]), xs[7] - hif(xs[7]));
        *(uint4*)&xH[go] = hp;
        *(uint4*)&xL[go] = lp;
    }
    __syncthreads();

    // L1: 64 -> 128
    {
        f32x4 acc1[2][2] = {};
        mlp_core<2, 2, 64, 128, 2>(acc1, xH, xL, W1tH, W1tL, 0, rowB, fg * 32, l);
        write_act<2, 128>(acc1, h1H, h1L, rowB, fg * 32, l);
    }
    __syncthreads();

    // L2 -> L3 streamed in three 128-feature passes; L3 accs persist in regs.
    // L3 as two FJ=2/D=2 calls (acc3a: feats fg*64..+31, acc3b: +32..+63).
    f32x4 acc3a[2][2] = {};
    f32x4 acc3b[2][2] = {};
    #pragma unroll
    for (int p = 0; p < 3; ++p) {
        if (p) __syncthreads();            // prior pass's L3 readers done
        {
            f32x4 acc2[2][2] = {};
            mlp_core<2, 4, 128, 384, 2>(acc2, h1H, h1L, W2tH, W2tL, 0,
                                        rowB, p * 128 + fg * 32, l);
            write_act<2, 128>(acc2, h2H, h2L, rowB, fg * 32, l);
        }
        __syncthreads();                   // h2 chunk ready
        mlp_core<2, 4, 128, 256, 2>(acc3a, h2H, h2L, W3tH, W3tL, p * 4,
                                    rowB, fg * 64, l);
        mlp_core<2, 4, 128, 256, 2>(acc3b, h2H, h2L, W3tH, W3tL, p * 4,
                                    rowB, fg * 64 + 32, l);
    }
    __syncthreads();                       // all h2/h1 readers done
    write_act<2, 256>(acc3a, h3H, h3L, rowB, fg * 64, l);        // h3 over h1+h2
    write_act<2, 256>(acc3b, h3H, h3L, rowB, fg * 64 + 32, l);
    __syncthreads();

    // L4: 256 -> 128
    {
        f32x4 acc4[2][2] = {};
        mlp_core<2, 8, 256, 128, 2>(acc4, h3H, h3L, WptH, WptL, 0, rowB, fg * 32, l);
        __syncthreads();                   // h3 readers done
        write_act<2, 128>(acc4, h4H, h4L, rowB, fg * 32, l);  // h4 over h3 start
    }
    __syncthreads();

    // tree level 7: 64 rows -> 16 parents, straight to global l7
    tree_level<1, 4, true>(h4H, h4L, waH, waL, woH, woL,
                           ops + 5461 + blk * 16, l7H, l7L,
                           blk * 16, 16, (w >> 1), (w & 1) * 64, l);
}

// ---------------- fused 3-level tree kernel: 128 child rows -> 2 parents --------
__global__ __launch_bounds__(512, 4) void tree3(
    const u16* __restrict__ inH, const u16* __restrict__ inL,   // [blocks*128][128]
    const u16* __restrict__ wAH, const u16* __restrict__ wAL,
    const u16* __restrict__ wOH, const u16* __restrict__ wOL,
    const int* __restrict__ ops0, const int* __restrict__ ops1,
    const int* __restrict__ ops2,
    u16* __restrict__ outH, u16* __restrict__ outL)             // [blocks*2][128]
{
    __shared__ u16 L0H[16384], L0L[16384];   // 128 rows (reused by level c out)
    __shared__ u16 L1H[4096],  L1L[4096];    // 32 rows

    const int tid = threadIdx.x;
    const int w = tid >> 6, l = tid & 63;
    const int blk = blockIdx.x;

    #pragma unroll
    for (int it = 0; it < 4; ++it) {
        int g = tid + it * 512;              // granule 0..2047
        int row = g >> 4, c4 = g & 15;
        size_t src = (size_t)(blk * 128 + row) * 128 + c4 * 8;
        int dst = act_g(128, row, c4) * 8;
        *(u16x8*)&L0H[dst] = *(const u16x8*)&inH[src];
        *(u16x8*)&L0L[dst] = *(const u16x8*)&inL[src];
    }
    __syncthreads();

    // level a: 128 rows -> 32 parents
    tree_level<2, 4, false>(L0H, L0L, wAH, wAL, wOH, wOL, ops0 + blk * 32,
                            L1H, L1L, 0, 32, (w & 3) * 2, (w >> 2) * 64, l);
    __syncthreads();
    // level b: 32 rows -> 8 parents (into L0 region, rows 0..7)
    tree_level<1, 2, false>(L1H, L1L, wAH, wAL, wOH, wOL, ops1 + blk * 8,
                            L0H, L0L, 0, 8, (w >> 2), (w & 3) * 32, l);
    __syncthreads();
    // level c: 8 rows -> 2 parents, to global
    tree_level<1, 1, true>(L0H, L0L, wAH, wAL, wOH, wOL, ops2 + blk * 2,
                           outH, outL, blk * 2, 2, 0, w * 16, l);
}

// ---------------- tail: level 0 + readout (fp32, float4 dots) ----------------
__global__ __launch_bounds__(128) void tail_final(
    const u16* __restrict__ l1H, const u16* __restrict__ l1L,   // [4][128]
    const int* __restrict__ ops,
    const float* __restrict__ Wand, const float* __restrict__ Wor,
    const float* __restrict__ Rw1, const float* __restrict__ Rb1,
    const float* __restrict__ Rw2, const float* __restrict__ Rb2,
    const float* __restrict__ Rw3, const float* __restrict__ Rb3,
    const float* __restrict__ Rwp, const float* __restrict__ Rbp,
    float* __restrict__ out)
{
    __shared__ float h[512];
    __shared__ float F[512];
    const int o = threadIdx.x;

    for (int i = o; i < 512; i += 128) h[i] = bf2f(l1H[i]) + bf2f(l1L[i]);
    __syncthreads();

    // level 0: root
    {
        const float* Wsel = (ops[0] == 0) ? Wand : Wor;
        const float4* wr = (const float4*)&Wsel[o * 128];
        const float4* h0 = (const float4*)&h[0];
        const float4* h1 = (const float4*)&h[128];
        const float4* h2 = (const float4*)&h[256];
        const float4* h3 = (const float4*)&h[384];
        float s0 = 0, s1 = 0, s2 = 0, s3 = 0;
        for (int m = 0; m < 32; ++m) {
            float4 wv = wr[m];
            float4 a0 = h0[m], a1 = h1[m], a2 = h2[m], a3 = h3[m];
            s0 += wv.x*a0.x + wv.y*a0.y + wv.z*a0.z + wv.w*a0.w;
            s1 += wv.x*a1.x + wv.y*a1.y + wv.z*a1.z + wv.w*a1.w;
            s2 += wv.x*a2.x + wv.y*a2.y + wv.z*a2.z + wv.w*a2.w;
            s3 += wv.x*a3.x + wv.y*a3.y + wv.z*a3.z + wv.w*a3.w;
        }
        F[o] = 0.25f * (tanh_p(s0) + tanh_p(s1) + tanh_p(s2) + tanh_p(s3));
    }
    __syncthreads();
    {
        const float4* wr = (const float4*)&Rw1[o * 128];
        const float4* xr = (const float4*)&F[0];
        float s = 0;
        for (int m = 0; m < 32; ++m) {
            float4 wv = wr[m], xv = xr[m];
            s += wv.x*xv.x + wv.y*xv.y + wv.z*xv.z + wv.w*xv.w;
        }
        __syncthreads();
        F[128 + o] = fmaxf(s + Rb1[o], 0.f);
    }
    __syncthreads();
    {
        const float4* wr = (const float4*)&Rw2[o * 128];
        const float4* xr = (const float4*)&F[128];
        float s = 0;
        for (int m = 0; m < 32; ++m) {
            float4 wv = wr[m], xv = xr[m];
            s += wv.x*xv.x + wv.y*xv.y + wv.z*xv.z + wv.w*xv.w;
        }
        __syncthreads();
        F[256 + o] = fmaxf(s + Rb2[o], 0.f);
    }
    __syncthreads();
    {
        const float4* wr = (const float4*)&Rw3[o * 128];
        const float4* xr = (const float4*)&F[256];
        float s = 0;
        for (int m = 0; m < 32; ++m) {
            float4 wv = wr[m], xv = xr[m];
            s += wv.x*xv.x + wv.y*xv.y + wv.z*xv.z + wv.w*xv.w;
        }
        __syncthreads();
        F[384 + o] = fmaxf(s + Rb3[o], 0.f) * Rwp[o];
    }
    __syncthreads();
    if (o == 0) {
        float t = 0.f;
        for (int i = 0; i < 128; ++i) t += F[384 + i];
        out[0] = t + Rbp[0];
    }
}

// ---------------- host launch ----------------
extern "C" void kernel_launch(void* const* d_in, const int* in_sizes, int n_in,
                              void* d_out, int out_size, void* d_ws, size_t ws_size,
                              hipStream_t stream)
{
    const float* inputs = (const float*)d_in[0];
    const int*   ops    = (const int*)d_in[1];
    const float* W1     = (const float*)d_in[2];
    const float* W2     = (const float*)d_in[3];
    const float* W3     = (const float*)d_in[4];
    const float* Wp     = (const float*)d_in[5];
    const float* Wand   = (const float*)d_in[6];
    const float* Wor    = (const float*)d_in[7];
    const float* Rw1    = (const float*)d_in[8];
    const float* Rb1    = (const float*)d_in[9];
    const float* Rw2    = (const float*)d_in[10];
    const float* Rb2    = (const float*)d_in[11];
    const float* Rw3    = (const float*)d_in[12];
    const float* Rb3    = (const float*)d_in[13];
    const float* Rwp    = (const float*)d_in[14];
    const float* Rbp    = (const float*)d_in[15];
    float* out = (float*)d_out;
    u16* ws = (u16*)d_ws;

    // ---- workspace layout (u16 elements) ----
    size_t off = 0;
    u16* w1tH = ws + off; off += 8192;   u16* w1tL = ws + off; off += 8192;
    u16* w2tH = ws + off; off += 49152;  u16* w2tL = ws + off; off += 49152;
    u16* w3tH = ws + off; off += 98304;  u16* w3tL = ws + off; off += 98304;
    u16* wptH = ws + off; off += 32768;  u16* wptL = ws + off; off += 32768;
    u16* waH  = ws + off; off += 16384;  u16* waL  = ws + off; off += 16384;
    u16* woH  = ws + off; off += 16384;  u16* woL  = ws + off; off += 16384;
    u16* l7H  = ws + off; off += (size_t)16384 * 128;
    u16* l7L  = ws + off; off += (size_t)16384 * 128;
    u16* l4H  = ws + off; off += 256 * 128;
    u16* l4L  = ws + off; off += 256 * 128;
    u16* l1H  = ws + off; off += 512;
    u16* l1L  = ws + off; off += 512;

    // ---- weight prep ----
    prep_all<<<108, 256, 0, stream>>>(W1, W2, W3, Wp, Wand, Wor,
        w1tH, w1tL, w2tH, w2tL, w3tH, w3tL, wptH, wptL, waH, waL, woH, woL);

    // ---- fused leaf MLP + tree level 7 (1024 blocks, 64KB LDS) ----
    leaf_fused<<<N_LEAVES / 64, 512, 0, stream>>>(
        inputs, w1tH, w1tL, w2tH, w2tL, w3tH, w3tL, wptH, wptL,
        waH, waL, woH, woL, ops, l7H, l7L);

    // ---- tree levels 6,5,4 (128 blocks) ----
    tree3<<<128, 512, 0, stream>>>(l7H, l7L, waH, waL, woH, woL,
        ops + 1365, ops + 341, ops + 85, l4H, l4L);

    // ---- tree levels 3,2,1 (2 blocks) ----
    tree3<<<2, 512, 0, stream>>>(l4H, l4L, waH, waL, woH, woL,
        ops + 21, ops + 5, ops + 1, l1H, l1L);

    // ---- level 0 + readout ----
    tail_final<<<1, 128, 0, stream>>>(l1H, l1L, ops, Wand, Wor,
        Rw1, Rb1, Rw2, Rb2, Rw3, Rb3, Rwp, Rbp, out);
}

// Round 16
// 133.863 us; speedup vs baseline: 1.0756x; 1.0615x over previous
//
#include <hip/hip_runtime.h>
#include <hip/hip_bf16.h>
#include <stdint.h>

#define N_LEAVES 65536
#define MEM 128
#define HID 128

typedef float  f32x4 __attribute__((ext_vector_type(4)));
typedef short  s16x8 __attribute__((ext_vector_type(8)));
typedef unsigned short u16;
typedef u16    u16x8 __attribute__((ext_vector_type(8)));

__device__ __forceinline__ u16 f2bf(float x) {
    unsigned u = __builtin_bit_cast(unsigned, x);
    u += 0x7FFFu + ((u >> 16) & 1u);          // RNE (prep only)
    return (u16)(u >> 16);
}
__device__ __forceinline__ float bf2f(u16 b) {
    unsigned u = ((unsigned)b) << 16;
    return __builtin_bit_cast(float, u);
}
// truncate-to-bf16 helpers (hi=trunc, lo captures err; combined rel ~2^-16)
__device__ __forceinline__ float hif(float x) {
    return __builtin_bit_cast(float, __builtin_bit_cast(unsigned, x) & 0xffff0000u);
}
// pack trunc-bf16 of (e0,e1) into one dword: low16=bf(e0), high16=bf(e1)
__device__ __forceinline__ unsigned packbf(float e0, float e1) {
    return __builtin_amdgcn_perm(__builtin_bit_cast(unsigned, e1),
                                 __builtin_bit_cast(unsigned, e0), 0x07060302u);
}
// cheap tanh (leaf): absolute err ~1e-7, fine for O(1)-norm activations
__device__ __forceinline__ float tanh_c(float x) {
    float E = __builtin_amdgcn_exp2f(x * 2.8853900817779268f);  // exp(2x)
    return 1.0f - 2.0f * __builtin_amdgcn_rcpf(E + 1.0f);
}
// tree tanh: full RELATIVE accuracy for small |x| (deep-tree h ~ 1e-5)
__device__ __forceinline__ float tanh_p(float x) {
    float x2 = x * x;
    float poly = x * (1.0f + x2 * (-0.33333334f + x2 * 0.13333334f));
    float E = __builtin_amdgcn_exp2f(x * 2.8853900817779268f);
    float ex = 1.0f - 2.0f * __builtin_amdgcn_rcpf(E + 1.0f);
    return (__builtin_fabsf(x) < 0.25f) ? poly : ex;
}

__device__ __forceinline__ f32x4 mfma_bf(s16x8 a, s16x8 b, f32x4 c) {
    return __builtin_amdgcn_mfma_f32_16x16x32_bf16(a, b, c, 0, 0, 0);
}

// ---------------- single prep kernel: split all 6 weights to k-major ----------------
// layout: [(k/8)*N + n]*8 + (k%8), hi/lo planes (RNE split).
__global__ __launch_bounds__(256) void prep_all(
    const float* __restrict__ W1, const float* __restrict__ W2,
    const float* __restrict__ W3, const float* __restrict__ Wp,
    const float* __restrict__ Wand, const float* __restrict__ Wor,
    u16* __restrict__ w1tH, u16* __restrict__ w1tL,
    u16* __restrict__ w2tH, u16* __restrict__ w2tL,
    u16* __restrict__ w3tH, u16* __restrict__ w3tL,
    u16* __restrict__ wptH, u16* __restrict__ wptL,
    u16* __restrict__ waH,  u16* __restrict__ waL,
    u16* __restrict__ woH,  u16* __restrict__ woL)
{
    int g = blockIdx.x * 256 + threadIdx.x;    // one granule (8 elems)
    const float* W; u16 *Th, *Tl; int K, N, base;
    if (g < 1024)       { W = W1;  Th = w1tH; Tl = w1tL; N = 128; K = 64;  base = 0; }
    else if (g < 7168)  { W = W2;  Th = w2tH; Tl = w2tL; N = 384; K = 128; base = 1024; }
    else if (g < 19456) { W = W3;  Th = w3tH; Tl = w3tL; N = 256; K = 384; base = 7168; }
    else if (g < 23552) { W = Wp;  Th = wptH; Tl = wptL; N = 128; K = 256; base = 19456; }
    else if (g < 25600) { W = Wand; Th = waH; Tl = waL;  N = 128; K = 128; base = 23552; }
    else if (g < 27648) { W = Wor;  Th = woH; Tl = woL;  N = 128; K = 128; base = 25600; }
    else return;
    int t = g - base;
    int kg8 = K >> 3;
    int n = t / kg8, kg = t - n * kg8;
    const float* src = &W[(size_t)n * K + kg * 8];
    size_t dst = ((size_t)kg * N + n) * 8;
    u16x8 hv, lv;
    #pragma unroll
    for (int j = 0; j < 8; ++j) {
        float v = src[j];
        u16 hb = f2bf(v);
        hv[j] = hb;
        lv[j] = f2bf(v - bf2f(hb));
    }
    *(u16x8*)&Th[dst] = hv;
    *(u16x8*)&Tl[dst] = lv;
}

// act LDS addressing: 16B granules, XOR-swizzled within each row's stripe.
__device__ __forceinline__ int act_g(int Wu, int row, int c4) {
    return row * (Wu >> 3) + (c4 ^ (row & 7));   // granule index
}

// ------ GEMM core: acc += W(A) x acts(B), 64 rows (RJ=4), FJ feat frags/wave ------
// WINU: act buffer width (u16). WSTR: weight N-stride. kt0: global k offset /32.
// Act buffer holds LOCAL k (kt 0..KTN-1); weights indexed at kt0+kt.
template<int FJ, int KTN, int WINU, int WSTR>
__device__ __forceinline__ void mlp_core(
    f32x4 (&acc)[FJ][4],
    const u16* inH, const u16* inL,
    const u16* __restrict__ BtH, const u16* __restrict__ BtL,
    int kt0, int featBase, int l)
{
    const int lr = l & 15, lc = l >> 4;
    s16x8 wh[2][FJ], wl[2][FJ];

    #pragma unroll
    for (int fi = 0; fi < FJ; ++fi) {
        int o = ((kt0 * 4 + lc) * WSTR + featBase + fi * 16 + lr) * 8;
        wh[0][fi] = *(const s16x8*)&BtH[o];
        wl[0][fi] = *(const s16x8*)&BtL[o];
    }

    #pragma unroll
    for (int kt = 0; kt < KTN; ++kt) {
        const int cur = kt & 1;
        if (kt + 1 < KTN) {
            #pragma unroll
            for (int fi = 0; fi < FJ; ++fi) {
                int o = (((kt0 + kt + 1) * 4 + lc) * WSTR + featBase + fi * 16 + lr) * 8;
                wh[cur ^ 1][fi] = *(const s16x8*)&BtH[o];
                wl[cur ^ 1][fi] = *(const s16x8*)&BtL[o];
            }
        }
        #pragma unroll
        for (int rj = 0; rj < 4; ++rj) {
            int off = act_g(WINU, rj * 16 + lr, kt * 4 + lc) * 8;
            s16x8 ah = *(const s16x8*)&inH[off];
            s16x8 al = *(const s16x8*)&inL[off];
            #pragma unroll
            for (int fi = 0; fi < FJ; ++fi) {
                f32x4 a = acc[fi][rj];
                a = mfma_bf(wh[cur][fi], ah, a);
                a = mfma_bf(wh[cur][fi], al, a);
                a = mfma_bf(wl[cur][fi], ah, a);
                acc[fi][rj] = a;
            }
        }
    }
}

// epilogue: tanh + trunc-split + perm-pack, to LDS act planes of width WOUTU
template<int FJ, int WOUTU>
__device__ __forceinline__ void write_act(
    f32x4 (&acc)[FJ][4], u16* outH, u16* outL, int featBase, int l)
{
    const int lr = l & 15, lc = l >> 4;
    #pragma unroll
    for (int fi = 0; fi < FJ; ++fi)
        #pragma unroll
        for (int rj = 0; rj < 4; ++rj) {
            int m  = rj * 16 + lr;
            int n0 = featBase + fi * 16 + lc * 4;
            f32x4 v = acc[fi][rj];
            float t0 = tanh_c(v[0]), t1 = tanh_c(v[1]);
            float t2 = tanh_c(v[2]), t3 = tanh_c(v[3]);
            uint2 hp, lp;
            hp.x = packbf(t0, t1);
            hp.y = packbf(t2, t3);
            lp.x = packbf(t0 - hif(t0), t1 - hif(t1));
            lp.y = packbf(t2 - hif(t2), t3 - hif(t3));
            int go = act_g(WOUTU, m, n0 >> 3) * 8 + (n0 & 7);
            *(uint2*)&outH[go] = hp;
            *(uint2*)&outL[go] = lp;
        }
}

// ---------------- one tree level (acts=A so lane's 4 D-rows = one parent) -------
template<int CJ, int FJ, bool TOGLOBAL>
__device__ __forceinline__ void tree_level(
    const u16* inH, const u16* inL,                   // LDS act planes, width 128
    const u16* __restrict__ wAH, const u16* __restrict__ wAL,
    const u16* __restrict__ wOH, const u16* __restrict__ wOL,  // k-major global
    const int* __restrict__ opsL,
    u16* outH, u16* outL,
    int outRowBase, int nValid, int cfBase, int ffBase, int l)
{
    const int lr = l & 15, lc = l >> 4;
    f32x4 accA[CJ][FJ] = {};
    f32x4 accO[CJ][FJ] = {};

    #pragma unroll
    for (int kt = 0; kt < 4; ++kt) {
        s16x8 ah[CJ], al[CJ];
        #pragma unroll
        for (int c = 0; c < CJ; ++c) {
            int off = act_g(128, (cfBase + c) * 16 + lr, kt * 4 + lc) * 8;
            ah[c] = *(const s16x8*)&inH[off];
            al[c] = *(const s16x8*)&inL[off];
        }
        #pragma unroll
        for (int f = 0; f < FJ; ++f) {
            int wo = ((kt * 4 + lc) * 128 + ffBase + f * 16 + lr) * 8;
            s16x8 bah = *(const s16x8*)&wAH[wo];
            s16x8 bal = *(const s16x8*)&wAL[wo];
            s16x8 boh = *(const s16x8*)&wOH[wo];
            s16x8 bol = *(const s16x8*)&wOL[wo];
            #pragma unroll
            for (int c = 0; c < CJ; ++c) {
                f32x4 a = accA[c][f];
                a = mfma_bf(ah[c], bah, a);
                a = mfma_bf(ah[c], bal, a);
                a = mfma_bf(al[c], bah, a);
                accA[c][f] = a;
                f32x4 o = accO[c][f];
                o = mfma_bf(ah[c], boh, o);
                o = mfma_bf(ah[c], bol, o);
                o = mfma_bf(al[c], boh, o);
                accO[c][f] = o;
            }
        }
    }

    #pragma unroll
    for (int c = 0; c < CJ; ++c) {
        int p = (cfBase + c) * 4 + lc;
        if (p < nValid) {
            int op = opsL[p];
            #pragma unroll
            for (int f = 0; f < FJ; ++f) {
                f32x4 v = op ? accO[c][f] : accA[c][f];
                float t = 0.25f * (tanh_p(v[0]) + tanh_p(v[1]) + tanh_p(v[2]) + tanh_p(v[3]));
                unsigned bits = __builtin_bit_cast(unsigned, t);
                u16 hb = (u16)(bits >> 16);
                float lof = t - __builtin_bit_cast(float, bits & 0xffff0000u);
                u16 lb = (u16)(__builtin_bit_cast(unsigned, lof) >> 16);
                int feat = ffBase + f * 16 + lr;
                if constexpr (TOGLOBAL) {
                    int ga = (outRowBase + p) * 128 + feat;
                    outH[ga] = hb;
                    outL[ga] = lb;
                } else {
                    int go = act_g(128, outRowBase + p, feat >> 3) * 8 + (feat & 7);
                    outH[go] = hb;
                    outL[go] = lb;
                }
            }
        }
    }
}

// --- fused leaf MLP + tree L7: 64 rows/block, 8 waves, 64KB LDS (2 blocks/CU) ---
// L2->L3 streamed through a 128-feature chunk buffer; L3 accumulates in regs.
__global__ __launch_bounds__(512, 4) void leaf_fused(
    const float* __restrict__ x,                 // [65536][64] fp32
    const u16* __restrict__ W1tH, const u16* __restrict__ W1tL,
    const u16* __restrict__ W2tH, const u16* __restrict__ W2tL,
    const u16* __restrict__ W3tH, const u16* __restrict__ W3tL,
    const u16* __restrict__ WptH, const u16* __restrict__ WptL,
    const u16* __restrict__ waH,  const u16* __restrict__ waL,
    const u16* __restrict__ woH,  const u16* __restrict__ woL,
    const int* __restrict__ ops,
    u16* __restrict__ l7H, u16* __restrict__ l7L) // [16384][128]
{
    __shared__ u16 pool[32768];   // 64 KB

    // regions (u16 offsets):
    u16* h1H = pool;               u16* h1L = pool + 8192;    // [0,16384)   w=128
    u16* xH  = pool + 16384;       u16* xL  = pool + 20480;   // [16384,24576) w=64
    u16* h2H = pool + 16384;       u16* h2L = pool + 24576;   // [16384,32768) w=128 (over x)
    u16* h3H = pool;               u16* h3L = pool + 16384;   // [0,32768)   w=256 (over h1+h2)
    u16* h4H = pool;               u16* h4L = pool + 8192;    // [0,16384)   w=128 (over h3)

    const int tid = threadIdx.x;
    const int w = tid >> 6, l = tid & 63;
    const int blk = blockIdx.x;
    const int rowBase = blk * 64;

    // stage x: 1 granule/thread, swizzled, trunc-split
    {
        int row = tid >> 3;
        int c0  = (tid & 7) * 8;
        const float* src = &x[(size_t)(rowBase + row) * 64 + c0];
        float4 v0 = *(const float4*)src;
        float4 v1 = *(const float4*)(src + 4);
        float xs[8] = {v0.x, v0.y, v0.z, v0.w, v1.x, v1.y, v1.z, v1.w};
        int go = act_g(64, row, c0 >> 3) * 8;
        uint4 hp, lp;
        hp.x = packbf(xs[0], xs[1]); hp.y = packbf(xs[2], xs[3]);
        hp.z = packbf(xs[4], xs[5]); hp.w = packbf(xs[6], xs[7]);
        lp.x = packbf(xs[0] - hif(xs[0]), xs[1] - hif(xs[1]));
        lp.y = packbf(xs[2] - hif(xs[2]), xs[3] - hif(xs[3]));
        lp.z = packbf(xs[4] - hif(xs[4]), xs[5] - hif(xs[5]));
        lp.w = packbf(xs[6] - hif(xs[6]), xs[7] - hif(xs[7]));
        *(uint4*)&xH[go] = hp;
        *(uint4*)&xL[go] = lp;
    }
    __syncthreads();

    // L1: 64 -> 128 (h1 disjoint from x -> write immediately)
    {
        f32x4 acc1[1][4] = {};
        mlp_core<1, 2, 64, 128>(acc1, xH, xL, W1tH, W1tL, 0, w * 16, l);
        write_act<1, 128>(acc1, h1H, h1L, w * 16, l);
    }
    __syncthreads();

    // L2 -> L3 streamed in three 128-feature passes; L3 accs persist in regs
    f32x4 acc3[2][4] = {};
    #pragma unroll
    for (int p = 0; p < 3; ++p) {
        if (p) __syncthreads();            // prior pass's L3 readers done
        {
            f32x4 acc2[1][4] = {};
            mlp_core<1, 4, 128, 384>(acc2, h1H, h1L, W2tH, W2tL, 0,
                                     p * 128 + w * 16, l);
            write_act<1, 128>(acc2, h2H, h2L, w * 16, l);
        }
        __syncthreads();                   // h2 chunk ready
        mlp_core<2, 4, 128, 256>(acc3, h2H, h2L, W3tH, W3tL, p * 4, w * 32, l);
    }
    __syncthreads();                       // all h2/h1 readers done
    write_act<2, 256>(acc3, h3H, h3L, w * 32, l);   // h3 over h1+h2 regions
    __syncthreads();

    // L4: 256 -> 128
    {
        f32x4 acc4[1][4] = {};
        mlp_core<1, 8, 256, 128>(acc4, h3H, h3L, WptH, WptL, 0, w * 16, l);
        __syncthreads();                   // h3 readers done
        write_act<1, 128>(acc4, h4H, h4L, w * 16, l);  // h4 over h3 start
    }
    __syncthreads();

    // tree level 7: 64 rows -> 16 parents, straight to global l7
    tree_level<1, 4, true>(h4H, h4L, waH, waL, woH, woL,
                           ops + 5461 + blk * 16, l7H, l7L,
                           blk * 16, 16, (w >> 1), (w & 1) * 64, l);
}

// ---------------- fused 3-level tree kernel: 128 child rows -> 2 parents --------
__global__ __launch_bounds__(512, 4) void tree3(
    const u16* __restrict__ inH, const u16* __restrict__ inL,   // [blocks*128][128]
    const u16* __restrict__ wAH, const u16* __restrict__ wAL,
    const u16* __restrict__ wOH, const u16* __restrict__ wOL,
    const int* __restrict__ ops0, const int* __restrict__ ops1,
    const int* __restrict__ ops2,
    u16* __restrict__ outH, u16* __restrict__ outL)             // [blocks*2][128]
{
    __shared__ u16 L0H[16384], L0L[16384];   // 128 rows (reused by level c out)
    __shared__ u16 L1H[4096],  L1L[4096];    // 32 rows

    const int tid = threadIdx.x;
    const int w = tid >> 6, l = tid & 63;
    const int blk = blockIdx.x;

    #pragma unroll
    for (int it = 0; it < 4; ++it) {
        int g = tid + it * 512;              // granule 0..2047
        int row = g >> 4, c4 = g & 15;
        size_t src = (size_t)(blk * 128 + row) * 128 + c4 * 8;
        int dst = act_g(128, row, c4) * 8;
        *(u16x8*)&L0H[dst] = *(const u16x8*)&inH[src];
        *(u16x8*)&L0L[dst] = *(const u16x8*)&inL[src];
    }
    __syncthreads();

    // level a: 128 rows -> 32 parents
    tree_level<2, 4, false>(L0H, L0L, wAH, wAL, wOH, wOL, ops0 + blk * 32,
                            L1H, L1L, 0, 32, (w & 3) * 2, (w >> 2) * 64, l);
    __syncthreads();
    // level b: 32 rows -> 8 parents (into L0 region, rows 0..7)
    tree_level<1, 2, false>(L1H, L1L, wAH, wAL, wOH, wOL, ops1 + blk * 8,
                            L0H, L0L, 0, 8, (w >> 2), (w & 3) * 32, l);
    __syncthreads();
    // level c: 8 rows -> 2 parents, to global
    tree_level<1, 1, true>(L0H, L0L, wAH, wAL, wOH, wOL, ops2 + blk * 2,
                           outH, outL, blk * 2, 2, 0, w * 16, l);
}

// ---------------- tail: level 0 + readout (fp32, float4 dots) ----------------
__global__ __launch_bounds__(128) void tail_final(
    const u16* __restrict__ l1H, const u16* __restrict__ l1L,   // [4][128]
    const int* __restrict__ ops,
    const float* __restrict__ Wand, const float* __restrict__ Wor,
    const float* __restrict__ Rw1, const float* __restrict__ Rb1,
    const float* __restrict__ Rw2, const float* __restrict__ Rb2,
    const float* __restrict__ Rw3, const float* __restrict__ Rb3,
    const float* __restrict__ Rwp, const float* __restrict__ Rbp,
    float* __restrict__ out)
{
    __shared__ float h[512];
    __shared__ float F[512];
    const int o = threadIdx.x;

    for (int i = o; i < 512; i += 128) h[i] = bf2f(l1H[i]) + bf2f(l1L[i]);
    __syncthreads();

    // level 0: root
    {
        const float* Wsel = (ops[0] == 0) ? Wand : Wor;
        const float4* wr = (const float4*)&Wsel[o * 128];
        const float4* h0 = (const float4*)&h[0];
        const float4* h1 = (const float4*)&h[128];
        const float4* h2 = (const float4*)&h[256];
        const float4* h3 = (const float4*)&h[384];
        float s0 = 0, s1 = 0, s2 = 0, s3 = 0;
        for (int m = 0; m < 32; ++m) {
            float4 wv = wr[m];
            float4 a0 = h0[m], a1 = h1[m], a2 = h2[m], a3 = h3[m];
            s0 += wv.x*a0.x + wv.y*a0.y + wv.z*a0.z + wv.w*a0.w;
            s1 += wv.x*a1.x + wv.y*a1.y + wv.z*a1.z + wv.w*a1.w;
            s2 += wv.x*a2.x + wv.y*a2.y + wv.z*a2.z + wv.w*a2.w;
            s3 += wv.x*a3.x + wv.y*a3.y + wv.z*a3.z + wv.w*a3.w;
        }
        F[o] = 0.25f * (tanh_p(s0) + tanh_p(s1) + tanh_p(s2) + tanh_p(s3));
    }
    __syncthreads();
    {
        const float4* wr = (const float4*)&Rw1[o * 128];
        const float4* xr = (const float4*)&F[0];
        float s = 0;
        for (int m = 0; m < 32; ++m) {
            float4 wv = wr[m], xv = xr[m];
            s += wv.x*xv.x + wv.y*xv.y + wv.z*xv.z + wv.w*xv.w;
        }
        __syncthreads();
        F[128 + o] = fmaxf(s + Rb1[o], 0.f);
    }
    __syncthreads();
    {
        const float4* wr = (const float4*)&Rw2[o * 128];
        const float4* xr = (const float4*)&F[128];
        float s = 0;
        for (int m = 0; m < 32; ++m) {
            float4 wv = wr[m], xv = xr[m];
            s += wv.x*xv.x + wv.y*xv.y + wv.z*xv.z + wv.w*xv.w;
        }
        __syncthreads();
        F[256 + o] = fmaxf(s + Rb2[o], 0.f);
    }
    __syncthreads();
    {
        const float4* wr = (const float4*)&Rw3[o * 128];
        const float4* xr = (const float4*)&F[256];
        float s = 0;
        for (int m = 0; m < 32; ++m) {
            float4 wv = wr[m], xv = xr[m];
            s += wv.x*xv.x + wv.y*xv.y + wv.z*xv.z + wv.w*xv.w;
        }
        __syncthreads();
        F[384 + o] = fmaxf(s + Rb3[o], 0.f) * Rwp[o];
    }
    __syncthreads();
    if (o == 0) {
        float t = 0.f;
        for (int i = 0; i < 128; ++i) t += F[384 + i];
        out[0] = t + Rbp[0];
    }
}

// ---------------- host launch ----------------
extern "C" void kernel_launch(void* const* d_in, const int* in_sizes, int n_in,
                              void* d_out, int out_size, void* d_ws, size_t ws_size,
                              hipStream_t stream)
{
    const float* inputs = (const float*)d_in[0];
    const int*   ops    = (const int*)d_in[1];
    const float* W1     = (const float*)d_in[2];
    const float* W2     = (const float*)d_in[3];
    const float* W3     = (const float*)d_in[4];
    const float* Wp     = (const float*)d_in[5];
    const float* Wand   = (const float*)d_in[6];
    const float* Wor    = (const float*)d_in[7];
    const float* Rw1    = (const float*)d_in[8];
    const float* Rb1    = (const float*)d_in[9];
    const float* Rw2    = (const float*)d_in[10];
    const float* Rb2    = (const float*)d_in[11];
    const float* Rw3    = (const float*)d_in[12];
    const float* Rb3    = (const float*)d_in[13];
    const float* Rwp    = (const float*)d_in[14];
    const float* Rbp    = (const float*)d_in[15];
    float* out = (float*)d_out;
    u16* ws = (u16*)d_ws;

    // ---- workspace layout (u16 elements) ----
    size_t off = 0;
    u16* w1tH = ws + off; off += 8192;   u16* w1tL = ws + off; off += 8192;
    u16* w2tH = ws + off; off += 49152;  u16* w2tL = ws + off; off += 49152;
    u16* w3tH = ws + off; off += 98304;  u16* w3tL = ws + off; off += 98304;
    u16* wptH = ws + off; off += 32768;  u16* wptL = ws + off; off += 32768;
    u16* waH  = ws + off; off += 16384;  u16* waL  = ws + off; off += 16384;
    u16* woH  = ws + off; off += 16384;  u16* woL  = ws + off; off += 16384;
    u16* l7H  = ws + off; off += (size_t)16384 * 128;
    u16* l7L  = ws + off; off += (size_t)16384 * 128;
    u16* l4H  = ws + off; off += 256 * 128;
    u16* l4L  = ws + off; off += 256 * 128;
    u16* l1H  = ws + off; off += 512;
    u16* l1L  = ws + off; off += 512;

    // ---- weight prep ----
    prep_all<<<108, 256, 0, stream>>>(W1, W2, W3, Wp, Wand, Wor,
        w1tH, w1tL, w2tH, w2tL, w3tH, w3tL, wptH, wptL, waH, waL, woH, woL);

    // ---- fused leaf MLP + tree level 7 (1024 blocks, 64KB LDS) ----
    leaf_fused<<<N_LEAVES / 64, 512, 0, stream>>>(
        inputs, w1tH, w1tL, w2tH, w2tL, w3tH, w3tL, wptH, wptL,
        waH, waL, woH, woL, ops, l7H, l7L);

    // ---- tree levels 6,5,4 (128 blocks) ----
    tree3<<<128, 512, 0, stream>>>(l7H, l7L, waH, waL, woH, woL,
        ops + 1365, ops + 341, ops + 85, l4H, l4L);

    // ---- tree levels 3,2,1 (2 blocks) ----
    tree3<<<2, 512, 0, stream>>>(l4H, l4L, waH, waL, woH, woL,
        ops + 21, ops + 5, ops + 1, l1H, l1L);

    // ---- level 0 + readout ----
    tail_final<<<1, 128, 0, stream>>>(l1H, l1L, ops, Wand, Wor,
        Rw1, Rb1, Rw2, Rb2, Rw3, Rb3, Rwp, Rbp, out);
}